// Round 9
// baseline (802.360 us; speedup 1.0000x reference)
//
#include <hip/hip_runtime.h>
#include <hip/hip_bf16.h>
#include <math.h>

// Problem constants: T=2048, B=4096, IN_S=1, H=20, OUT_S=1
#define TT 2048
#define BB 4096
#define HH 20

typedef float v2f __attribute__((ext_vector_type(2)));

#define L2E 1.4426950408889634f  // log2(e)

__device__ __forceinline__ float rcp_fast(float x)  { return __builtin_amdgcn_rcpf(x); }
__device__ __forceinline__ float exp2_fast(float x) { return __builtin_amdgcn_exp2f(x); }

// Backend selects v_pk_fma_f32 — no inline-asm pinning of the FMA (R5 lesson).
__device__ __forceinline__ v2f pk_fma(v2f a, v2f b, v2f c) {
    return __builtin_elementwise_fma(a, b, c);
}

// R17: PHASE-STAGGERED two waves per SIMD, light 2-batch waves.
// Evidence chain: R10 geometry (2 batches/wave, issue ~300cy) measured
// cadence 960cy at 2 waves/SIMD, vs single-wave-chain estimate ~670cy.
// The ~290cy interference ~= the partner wave's ENTIRE issue — signature of
// PHASE-LOCK: co-resident waves run identical instruction streams, start
// together, stall at the same instants; neither can fill the other's stall
// windows. R14's win (870cy, 742us) came from removing the locked partner
// (1 wave/SIMD), not from amortization. If lock is the mechanism, a one-time
// start-offset of ~half a step should let each wave's issue land in its
// partner's stalls: cadence -> max(C_single ~670, sum-issue ~600) ~ 700cy.
// Stagger: ph = (bid + (bid>>10)) & 3 -> s_sleep {0,192,384,576}cy. The mix
// makes both plausible pairings (i,i+1) and (i,i+1024) get distinct phases.
// R16 post-mortem: in-loop pins neutral, VGPR stayed 124 — AGPR-move theory
// dead (VOP3P sources the acc-half directly). R15: source reorder no-op.
// R13: bpermute dead. Model: wall = T x cadence(per-SIMD step).
__global__ __launch_bounds__(64, 2) void lstm_fused_kernel(
    const float* __restrict__ u,      // [T, B, 1]
    const float* __restrict__ W_ih,   // [4H, 1]
    const float* __restrict__ W_hh,   // [4H, H]
    const float* __restrict__ W_out,  // [1, H]
    float* __restrict__ y)            // [T, B, 1]
{
    // ---- one-time start stagger (de-phase co-resident waves) ----
    {
        const int ph = (blockIdx.x + (blockIdx.x >> 10)) & 3;
        if (ph == 1)      __builtin_amdgcn_s_sleep(3);   // ~192 cy
        else if (ph == 2) __builtin_amdgcn_s_sleep(6);   // ~384 cy
        else if (ph == 3) __builtin_amdgcn_s_sleep(9);   // ~576 cy
    }

    // Single buffer. Compiler SEES the aliasing between write and reads ->
    // inserts the lgkmcnt wait itself (R6-verified correct; R7 showed
    // __restrict__ LDS pointers suppress it -> stale h).
    __shared__ __align__(16) float hbuf[4][HH];

    const int lane  = threadIdx.x;
    const int group = lane / HH;          // 0..3 (2,3 == y/idle)
    const int j     = lane - group * HH;  // 0..19
    const bool is_y = (lane >= 2 * HH) && (lane < 2 * HH + 2);  // lanes 40,41
    const int b_real = blockIdx.x * 2 + group;
    const bool active = (group < 2) && (b_real < BB);
    const int b = active ? b_real : 0;

    // h_{-1} = 0 (all groups incl. idle regions).
    for (int i = lane; i < 4 * HH; i += 64) ((float*)hbuf)[i] = 0.0f;
    asm volatile("" ::: "memory");  // one-time, outside the hot loop

    // ---- Weights in registers, packed along k: wg[g][m] = (w[2m], w[2m+1]).
    // Pre-scaled into exp2 domain: i,f,o rows * -log2(e); g row * -2*log2(e).
    v2f wg[4][HH / 2];
    const float gsc[4] = {-L2E, -L2E, -2.0f * L2E, -L2E};
    #pragma unroll
    for (int g = 0; g < 4; ++g) {
        #pragma unroll
        for (int m = 0; m < HH / 2; ++m) {
            wg[g][m].x = gsc[g] * W_hh[(g * HH + j) * HH + 2 * m];
            wg[g][m].y = gsc[g] * W_hh[(g * HH + j) * HH + 2 * m + 1];
        }
    }
    v2f wih2[4];
    #pragma unroll
    for (int g = 0; g < 4; ++g) { wih2[g].x = gsc[g] * W_ih[g * HH + j]; wih2[g].y = 0.0f; }

    // y-offload wiring: broadcast-source group per lane, W_out row for y-lanes.
    int bg = group;
    if (lane >= 2 * HH) {
        bg = is_y ? (lane - 2 * HH) : 2;  // lane40->group0's h, lane41->group1's
        if (is_y) {
            #pragma unroll
            for (int m = 0; m < HH / 2; ++m) {
                wg[0][m].x = W_out[2 * m];      // UNSCALED: a0 = dot(W_out, h)
                wg[0][m].y = W_out[2 * m + 1];
            }
            wih2[0].x = 0.0f;  // y has no u-term
        }
    }
    const v2f* hs = (const v2f*)(&hbuf[bg][0]);  // no restrict: must alias

    float c = 0.0f;
    const float* __restrict__ up = u + b;
    float* yp = y + blockIdx.x * 2 + (lane - 2 * HH);  // valid only on y-lanes

    float u_cur[8];
    #pragma unroll
    for (int k = 0; k < 8; ++k) u_cur[k] = up[(size_t)k * BB];

    for (int t8 = 0; t8 < TT; t8 += 8) {
        const int tn = (t8 + 8 < TT) ? (t8 + 8) : t8;
        float u_nxt[8];
        #pragma unroll
        for (int k = 0; k < 8; ++k) u_nxt[k] = up[(size_t)(tn + k) * BB];

        float y8[8];  // on y-lanes: y8[tt] = y_{t8+tt-1} (h broadcast read is one step late)

        #pragma unroll
        for (int tt = 0; tt < 8; ++tt) {
            // ---- read h_{t-1} as 10 pairs (compiler merges to ds_read_b128) ----
            v2f h2[10];
            #pragma unroll
            for (int m = 0; m < 10; ++m) h2[m] = hs[m];

            const float uv = u_cur[tt];
            const v2f uv2 = {uv, uv};
            v2f a0 = wih2[0] * uv2;   // v_pk_mul_f32; .y term is 0
            v2f a1 = wih2[1] * uv2;
            v2f a2 = wih2[2] * uv2;
            v2f a3 = wih2[3] * uv2;

            // 40 v_pk_fma_f32; 4 accumulators round-robin -> dep spacing
            // 4 insts (8 cyc) > 4-cyc FMA latency.
            #pragma unroll
            for (int m = 0; m < 10; ++m) {
                v2f hp = h2[m];
                a2 = pk_fma(wg[2][m], hp, a2);
                a1 = pk_fma(wg[1][m], hp, a1);
                a0 = pk_fma(wg[0][m], hp, a0);
                a3 = pk_fma(wg[3][m], hp, a3);
            }
            const float g2 = a2.x + a2.y;  // exp2-domain pre-acts
            const float g1 = a1.x + a1.y;
            const float g0 = a0.x + a0.y;  // (y-lanes: y value)
            const float g3 = a3.x + a3.y;
            y8[tt] = g0;                   // only consumed on y-lanes

            // ---- activations: 5 exp2, 2 rcp (merged denominators) ----
            const float eg = exp2_fast(g2);   // e^{-2 x_g}  (sign-safe: |x_g|<~6)
            const float ef = exp2_fast(g1);   // e^{-x_f}
            const float ei = exp2_fast(g0);   // e^{-x_i}
            const float eo = exp2_fast(g3);   // e^{-x_o}
            const float pg  = 1.0f + eg;
            const float pf  = 1.0f + ef;
            const float pi_ = 1.0f + ei;
            const float po  = 1.0f + eo;
            const float mg  = 1.0f - eg;      // sign of tanh(x_g) falls out naturally

            // c' = f*c + i*tanh(g), one rcp. c itself retires OFF the h-path:
            // tanh(c') needs only |num| (|c'| = |num|*r, r>0) and sign(num).
            const float m1  = pg * pi_;
            const float num = fmaf(c, m1, mg * pf);
            const float r   = rcp_fast(pf * m1);
            c = num * r;                               // for next step only
            const float kn  = (-2.0f * L2E) * fabsf(num);  // overlaps the rcp
            const float ec  = exp2_fast(kn * r);       // e^{-2|c|} <= 1, no overflow
            const float pc  = 1.0f + ec;
            const float mcs = copysignf(1.0f - ec, num);   // sign(c)==sign(num)
            const float h   = mcs * rcp_fast(po * pc);

            // ---- broadcast h_t. NO asm barrier: alias analysis orders the
            // LDS write vs next step's reads (R6-verified). ----
            hbuf[group][j] = h;
        }

        if (is_y) {
            #pragma unroll
            for (int k = 0; k < 8; ++k) {
                const int idx = t8 - 1 + k;
                if (idx >= 0) yp[(size_t)idx * BB] = y8[k];
            }
        }

        #pragma unroll
        for (int k = 0; k < 8; ++k) u_cur[k] = u_nxt[k];
    }

    // Epilogue: y_{T-1} from the final h broadcast (y-lanes only).
    {
        v2f ay = {0.0f, 0.0f};
        #pragma unroll
        for (int m = 0; m < 10; ++m) ay = pk_fma(wg[0][m], hs[m], ay);
        if (is_y) yp[(size_t)(TT - 1) * BB] = ay.x + ay.y;
    }
}

extern "C" void kernel_launch(void* const* d_in, const int* in_sizes, int n_in,
                              void* d_out, int out_size, void* d_ws, size_t ws_size,
                              hipStream_t stream) {
    const float* u     = (const float*)d_in[0];   // [2048, 4096, 1]
    const float* W_ih  = (const float*)d_in[1];   // [80, 1]
    const float* W_hh  = (const float*)d_in[2];   // [80, 20]
    const float* W_out = (const float*)d_in[3];   // [1, 20]
    float* y = (float*)d_out;                      // [2048, 4096, 1]

    const int blocks = BB / 2;  // 2 batches per single-wave block -> 2048 = 2 waves/SIMD
    lstm_fused_kernel<<<dim3(blocks), dim3(64), 0, stream>>>(u, W_ih, W_hh, W_out, y);
}